// Round 18
// baseline (77.556 us; speedup 1.0000x reference)
//
#include <hip/hip_runtime.h>

#define NB 64
#define NN 4096
#define NC 128
#define NH 4
#define HC (NH * NC)        // 512
#define PSTRIDE (8 + HC)    // 520 floats per partial
#define NSLICE 16           // 16*64 = 1024 blocks for kB
#define TROWS 64            // rows per LDS tile (32 KB)
#define NROWA 128           // rows per kA block
#define LRELU 0.2f

// ws float layout: [0,520) wtbt | [520, 520+NB*NSLICE*PSTRIDE) part | then pArr [B*N*4]
#define WS_PART 520
#define WS_P    (WS_PART + NB * NSLICE * PSTRIDE)

// ---------------- k0: wt[k][h] = sum_c W[k, h*C+c] * t[h,c];  bt[h] = sum_c bias*t.
__global__ __launch_bounds__(128) void k0_wt(const float* __restrict__ W,
                                             const float* __restrict__ bias,
                                             const float* __restrict__ tune,
                                             float* __restrict__ wtbt)
{
    const int bid = blockIdx.x;
    const int t = threadIdx.x;                       // 0..127
    const float* src = (bid < NC) ? (W + (size_t)bid * HC) : bias;
    float* dst = (bid < NC) ? (wtbt + bid * NH) : (wtbt + NC * NH);
    const float4 a = reinterpret_cast<const float4*>(src)[t];
    const float4 b = reinterpret_cast<const float4*>(tune)[t];
    float p = a.x * b.x + a.y * b.y + a.z * b.z + a.w * b.w;
    #pragma unroll
    for (int off = 16; off; off >>= 1) p += __shfl_xor(p, off, 32);
    if ((t & 31) == 0) dst[t >> 5] = p;              // group t>>5 == head h
}

// ---------------- kA: logits map. Half-wave per row; lane = h*8+j owns features
// [16j,16j+16) of head h; 3-shuffle butterfly; p = exp(leaky(x)) stored to pArr.
// Rows fully independent (no accumulators) -> deep pipelining + TLP hides the chain.
// gs ignored here: invalid rows get finite garbage p, masked in kB.
__global__ __launch_bounds__(256, 4) void kA_logits(const float* __restrict__ V,
                                                    const float* __restrict__ wtbt,
                                                    float* __restrict__ pArr)
{
    const int tid = threadIdx.x;
    const int hw = tid >> 5;
    const int lane = tid & 31;
    const int h = lane >> 3;
    const int j = lane & 7;

    float wtk[16];
    #pragma unroll
    for (int u = 0; u < 16; ++u) wtk[u] = wtbt[(16 * j + u) * NH + h];
    const float bt = wtbt[HC + h];

    const int base = blockIdx.x * NROWA;
    #pragma unroll 2
    for (int it = 0; it < NROWA / 8; ++it) {
        const int row = base + it * 8 + hw;          // flat row in [0, B*N)
        const float4* vr = reinterpret_cast<const float4*>(V + (size_t)row * NC + j * 16);
        const float4 A0 = vr[0];
        const float4 A1 = vr[1];
        const float4 A2 = vr[2];
        const float4 A3 = vr[3];
        float a0 = A0.x * wtk[0]  + A0.y * wtk[1]  + A0.z * wtk[2]  + A0.w * wtk[3];
        float a1 = A1.x * wtk[4]  + A1.y * wtk[5]  + A1.z * wtk[6]  + A1.w * wtk[7];
        float a2 = A2.x * wtk[8]  + A2.y * wtk[9]  + A2.z * wtk[10] + A2.w * wtk[11];
        float a3 = A3.x * wtk[12] + A3.y * wtk[13] + A3.z * wtk[14] + A3.w * wtk[15];
        float lg = (a0 + a1) + (a2 + a3);
        lg += __shfl_xor(lg, 1, 32);
        lg += __shfl_xor(lg, 2, 32);
        lg += __shfl_xor(lg, 4, 32);   // 8-lane head group holds full logit
        float x = lg + bt;
        x = (x >= 0.f) ? x : LRELU * x;               // leaky_relu
        const float p = __expf(x);                    // no max subtraction (est. safe)
        if (j == 0) pArr[(size_t)row * NH + h] = p;
    }
}

// ---------------- kB: r15's LDS-staged accumulate, logit section replaced by a
// p-load from pArr -> inner loop = ds_read + FMA only (no shuffles / exp / branches).
__global__ __launch_bounds__(256, 4) void kB_acc(const float* __restrict__ V,
                                                 const int* __restrict__ gs,
                                                 const float* __restrict__ pArr,
                                                 float* __restrict__ part)
{
    __shared__ float smem[8192];                     // 32 KB, unioned
    float (*Vt)[NC] = reinterpret_cast<float(*)[NC]>(smem);          // [64][128]
    float (*Sall)[NH][132] = reinterpret_cast<float(*)[NH][132]>(smem); // [8][4][132]
    float* llds = smem + 8 * NH * 132;               // 32 floats

    const int slice = blockIdx.x;
    const int b = blockIdx.y;
    const int tid = threadIdx.x;
    const int hw = tid >> 5;          // half-wave 0..7
    const int lane = tid & 31;
    const int h = lane >> 3;          // head 0..3
    const int j = lane & 7;           // feature-group (features 16j..16j+15)
    const int gsz = gs[b];

    const int segB = (gsz + NSLICE - 1) / NSLICE;    // rows per block
    const int myBeg = slice * segB;
    int myEnd = myBeg + segB;
    if (myEnd > gsz) myEnd = gsz;
    const int nrows = (myEnd > myBeg) ? (myEnd - myBeg) : 0;
    const int ntile = (nrows + TROWS - 1) / TROWS;

    float l = 0.f;
    float S[16] = {};

    const float4* Vg4 = reinterpret_cast<const float4*>(V);
    const size_t gbase = (size_t)b * NN;

    for (int tile = 0; tile < ntile; ++tile) {
        const int tbase = myBeg + tile * TROWS;
        // ---- stage: 2048 float4; thread t does idx = t + 256k (8 independent loads)
        float4 r[8];
        #pragma unroll
        for (int k = 0; k < 8; ++k) {
            const int idx = tid + (k << 8);
            const int row = idx >> 5;                 // 0..63
            const int gr = tbase + row;
            const int src_row = (gr < myEnd) ? gr : myBeg;   // clamp (masked later)
            r[k] = Vg4[(gbase + src_row) * 32 + (idx & 31)];
        }
        #pragma unroll
        for (int k = 0; k < 8; ++k) {
            const int idx = tid + (k << 8);
            reinterpret_cast<float4*>(smem)[idx] = r[k];
        }
        __syncthreads();
        // ---- compute: half-wave hw handles rows hw*8 .. hw*8+7 from LDS.
        //      p comes from pArr (L2-hot) -> NO cross-lane ops in this loop.
        #pragma unroll 2
        for (int rr = 0; rr < 8; ++rr) {
            const int row = (hw << 3) + rr;
            const bool valid = (tbase + row < myEnd);
            const float4* vr = reinterpret_cast<const float4*>(&Vt[row][j * 16]);
            const float4 A0 = vr[0];
            const float4 A1 = vr[1];
            const float4 A2 = vr[2];
            const float4 A3 = vr[3];
            float p = pArr[(gbase + tbase + row) * NH + h];
            p = valid ? p : 0.f;
            l += p;
            S[0]  += p * A0.x;  S[1]  += p * A0.y;  S[2]  += p * A0.z;  S[3]  += p * A0.w;
            S[4]  += p * A1.x;  S[5]  += p * A1.y;  S[6]  += p * A1.z;  S[7]  += p * A1.w;
            S[8]  += p * A2.x;  S[9]  += p * A2.y;  S[10] += p * A2.z;  S[11] += p * A2.w;
            S[12] += p * A3.x;  S[13] += p * A3.y;  S[14] += p * A3.z;  S[15] += p * A3.w;
        }
        __syncthreads();                              // Vt free for next stage
    }

    // ---- block combine across 8 half-waves (smem reused: Sall/llds)
    if (j == 0) llds[hw * NH + h] = l;
    #pragma unroll
    for (int t = 0; t < 4; ++t) {
        float4 s4;
        s4.x = S[4 * t]; s4.y = S[4 * t + 1]; s4.z = S[4 * t + 2]; s4.w = S[4 * t + 3];
        *reinterpret_cast<float4*>(&Sall[hw][h][16 * j + 4 * t]) = s4;
    }
    __syncthreads();
    float* pb = part + (size_t)(b * NSLICE + slice) * PSTRIDE;
    if (tid < 4) {
        float L = 0.f;
        #pragma unroll
        for (int ww = 0; ww < 8; ++ww) L += llds[ww * NH + tid];
        pb[4 + tid] = L;
    }
    #pragma unroll
    for (int r2 = 0; r2 < 2; ++r2) {
        const int e = tid + r2 * 256;
        const int hh = e >> 7, k = e & 127;
        float s = 0.f;
        #pragma unroll
        for (int ww = 0; ww < 8; ++ww) s += Sall[ww][hh][k];
        pb[8 + e] = s;
    }
}

// ---------------- k2: block (b, h): merge NSLICE partials for head h, then
// out[b, h*128+d] = (S[h]/L[h]) . W[:, h*128+d] + bias[h*128+d]
__global__ __launch_bounds__(128) void k2_out(const float* __restrict__ part,
                                              const float* __restrict__ W,
                                              const float* __restrict__ bias,
                                              float* __restrict__ out)
{
    const int b = blockIdx.x;
    const int h = blockIdx.y;
    const int tid = threadIdx.x;     // 0..127
    const float* pb = part + (size_t)b * NSLICE * PSTRIDE;

    __shared__ float Sn[NC];
    __shared__ float sL;
    if (tid == 0) {
        float L = 0.f;
        #pragma unroll
        for (int c = 0; c < NSLICE; ++c) L += pb[(size_t)c * PSTRIDE + 4 + h];
        sL = L;
    }
    __syncthreads();
    {
        float s = 0.f;
        #pragma unroll 4
        for (int c = 0; c < NSLICE; ++c)
            s += pb[(size_t)c * PSTRIDE + 8 + h * NC + tid];
        Sn[tid] = s / sL;
    }
    __syncthreads();
    const int d = h * NC + tid;
    float acc = 0.f;
    #pragma unroll 4
    for (int k = 0; k < NC; ++k) acc += Sn[k] * W[(size_t)k * HC + d];
    out[(size_t)b * HC + d] = acc + bias[d];
}

extern "C" void kernel_launch(void* const* d_in, const int* in_sizes, int n_in,
                              void* d_out, int out_size, void* d_ws, size_t ws_size,
                              hipStream_t stream)
{
    const float* V    = (const float*)d_in[0];
    const int*   gsz  = (const int*)d_in[1];
    const float* W    = (const float*)d_in[2];
    const float* bias = (const float*)d_in[3];
    const float* tune = (const float*)d_in[4];
    float* out  = (float*)d_out;
    float* ws   = (float*)d_ws;
    float* wtbt = ws;
    float* part = ws + WS_PART;
    float* pArr = ws + WS_P;               // B*N*4 floats = 4 MB

    hipLaunchKernelGGL(k0_wt, dim3(NC + 1), dim3(128), 0, stream, W, bias, tune, wtbt);
    hipLaunchKernelGGL(kA_logits, dim3(NB * NN / NROWA), dim3(256), 0, stream, V, wtbt, pArr);
    hipLaunchKernelGGL(kB_acc, dim3(NSLICE, NB), dim3(256), 0, stream, V, gsz, pArr, part);
    hipLaunchKernelGGL(k2_out, dim3(NB, NH), dim3(128), 0, stream, part, W, bias, out);
}

// Round 19
// 64.776 us; speedup vs baseline: 1.1973x; 1.1973x over previous
//
#include <hip/hip_runtime.h>

#define NB 64
#define NN 4096
#define NC 128
#define NH 4
#define HC (NH * NC)        // 512
#define PSTRIDE (8 + HC)    // 520 floats per partial
#define NSLICE 32           // 32 windows/graph -> 2048 blocks
#define WROWS 128           // rows per block window
#define LRELU 0.2f

// ---------------- k0: wt[k][h] = sum_c W[k, h*C+c] * t[h,c];  bt[h] = sum_c bias*t.
__global__ __launch_bounds__(128) void k0_wt(const float* __restrict__ W,
                                             const float* __restrict__ bias,
                                             const float* __restrict__ tune,
                                             float* __restrict__ wtbt)
{
    const int bid = blockIdx.x;
    const int t = threadIdx.x;                       // 0..127
    const float* src = (bid < NC) ? (W + (size_t)bid * HC) : bias;
    float* dst = (bid < NC) ? (wtbt + bid * NH) : (wtbt + NC * NH);
    const float4 a = reinterpret_cast<const float4*>(src)[t];
    const float4 b = reinterpret_cast<const float4*>(tune)[t];
    float p = a.x * b.x + a.y * b.y + a.z * b.z + a.w * b.w;
    #pragma unroll
    for (int off = 16; off; off >>= 1) p += __shfl_xor(p, off, 32);
    if ((t & 31) == 0) dst[t >> 5] = p;              // group t>>5 == head h
}

// ---------------- k1: kA-structure + accumulate. Block (slice,b) owns contiguous
// window [slice*128, +128); half-wave hw handles rows win + 8*it + hw (block walks
// its window sequentially, 4KB per step). FREE-RUNNING: no LDS/barriers in the hot
// loop; iteration addresses are base + it*stride (independent -> loads pipeline).
// Register-only accumulate; window blocks beyond gs early-exit to zero partial.
__global__ __launch_bounds__(256, 4) void k1_part(const float* __restrict__ V,
                                                  const int* __restrict__ gs,
                                                  const float* __restrict__ wtbt,
                                                  float* __restrict__ part)
{
    const int slice = blockIdx.x;
    const int b = blockIdx.y;
    const int tid = threadIdx.x;
    const int hw = tid >> 5;          // half-wave 0..7
    const int lane = tid & 31;
    const int h = lane >> 3;          // head 0..3
    const int j = lane & 7;           // feature-group (features 16j..16j+15)
    const int gsz = gs[b];
    const int win = slice * WROWS;

    float l = 0.f;
    float S[16] = {};

    if (win < gsz) {                  // block has work
        float wtk[16];
        #pragma unroll
        for (int u = 0; u < 16; ++u) wtk[u] = wtbt[(16 * j + u) * NH + h];
        const float bt = wtbt[HC + h];

        const int rem = gsz - win - hw;
        int it_n = rem > 0 ? ((rem + 7) >> 3) : 0;
        if (it_n > WROWS / 8) it_n = WROWS / 8;      // <= 16

        const float* vbase = V + ((size_t)b * NN + win + hw) * NC + j * 16;

        #pragma unroll 2
        for (int it = 0; it < it_n; ++it) {
            const float4* vr = reinterpret_cast<const float4*>(vbase + (size_t)it * 8 * NC);
            const float4 A0 = vr[0];
            const float4 A1 = vr[1];
            const float4 A2 = vr[2];
            const float4 A3 = vr[3];
            float a0 = A0.x * wtk[0]  + A0.y * wtk[1]  + A0.z * wtk[2]  + A0.w * wtk[3];
            float a1 = A1.x * wtk[4]  + A1.y * wtk[5]  + A1.z * wtk[6]  + A1.w * wtk[7];
            float a2 = A2.x * wtk[8]  + A2.y * wtk[9]  + A2.z * wtk[10] + A2.w * wtk[11];
            float a3 = A3.x * wtk[12] + A3.y * wtk[13] + A3.z * wtk[14] + A3.w * wtk[15];
            float lg = (a0 + a1) + (a2 + a3);
            lg += __shfl_xor(lg, 1, 32);
            lg += __shfl_xor(lg, 2, 32);
            lg += __shfl_xor(lg, 4, 32);   // 8-lane head group holds full logit
            float x = lg + bt;
            x = (x >= 0.f) ? x : LRELU * x;           // leaky_relu
            const float p = __expf(x);                // no max subtraction (safe: |x|<~8)
            l += p;
            S[0]  += p * A0.x;  S[1]  += p * A0.y;  S[2]  += p * A0.z;  S[3]  += p * A0.w;
            S[4]  += p * A1.x;  S[5]  += p * A1.y;  S[6]  += p * A1.z;  S[7]  += p * A1.w;
            S[8]  += p * A2.x;  S[9]  += p * A2.y;  S[10] += p * A2.z;  S[11] += p * A2.w;
            S[12] += p * A3.x;  S[13] += p * A3.y;  S[14] += p * A3.z;  S[15] += p * A3.w;
        }
    }

    // ---- block combine across 8 half-waves (LDS only here, after the hot loop)
    __shared__ float llds[8][4];
    __shared__ float Sall[8][4][132];    // padded
    if (j == 0) llds[hw][h] = l;
    #pragma unroll
    for (int t = 0; t < 4; ++t) {
        float4 s4;
        s4.x = S[4 * t]; s4.y = S[4 * t + 1]; s4.z = S[4 * t + 2]; s4.w = S[4 * t + 3];
        *reinterpret_cast<float4*>(&Sall[hw][h][16 * j + 4 * t]) = s4;
    }
    __syncthreads();
    float* pb = part + (size_t)(b * NSLICE + slice) * PSTRIDE;
    if (tid < 4) {
        float L = 0.f;
        #pragma unroll
        for (int ww = 0; ww < 8; ++ww) L += llds[ww][tid];
        pb[4 + tid] = L;
    }
    #pragma unroll
    for (int r2 = 0; r2 < 2; ++r2) {
        const int e = tid + r2 * 256;
        const int hh = e >> 7, k = e & 127;
        float s = 0.f;
        #pragma unroll
        for (int ww = 0; ww < 8; ++ww) s += Sall[ww][hh][k];
        pb[8 + e] = s;
    }
}

// ---------------- k2: block (b, h): merge NSLICE partials for head h, then
// out[b, h*128+d] = (S[h]/L[h]) . W[:, h*128+d] + bias[h*128+d]
__global__ __launch_bounds__(128) void k2_out(const float* __restrict__ part,
                                              const float* __restrict__ W,
                                              const float* __restrict__ bias,
                                              float* __restrict__ out)
{
    const int b = blockIdx.x;
    const int h = blockIdx.y;
    const int tid = threadIdx.x;     // 0..127
    const float* pb = part + (size_t)b * NSLICE * PSTRIDE;

    __shared__ float Sn[NC];
    __shared__ float sL;
    if (tid == 0) {
        float L = 0.f;
        #pragma unroll 8
        for (int c = 0; c < NSLICE; ++c) L += pb[(size_t)c * PSTRIDE + 4 + h];
        sL = L;
    }
    __syncthreads();
    {
        float s = 0.f;
        #pragma unroll 8
        for (int c = 0; c < NSLICE; ++c)
            s += pb[(size_t)c * PSTRIDE + 8 + h * NC + tid];
        Sn[tid] = s / sL;
    }
    __syncthreads();
    const int d = h * NC + tid;
    float acc = 0.f;
    #pragma unroll 4
    for (int k = 0; k < NC; ++k) acc += Sn[k] * W[(size_t)k * HC + d];
    out[(size_t)b * HC + d] = acc + bias[d];
}

extern "C" void kernel_launch(void* const* d_in, const int* in_sizes, int n_in,
                              void* d_out, int out_size, void* d_ws, size_t ws_size,
                              hipStream_t stream)
{
    const float* V    = (const float*)d_in[0];
    const int*   gsz  = (const int*)d_in[1];
    const float* W    = (const float*)d_in[2];
    const float* bias = (const float*)d_in[3];
    const float* tune = (const float*)d_in[4];
    float* out  = (float*)d_out;
    float* wtbt = (float*)d_ws;            // 520 floats (516 used)
    float* part = wtbt + PSTRIDE;          // NB*NSLICE*PSTRIDE floats (~4.3 MB)

    hipLaunchKernelGGL(k0_wt, dim3(NC + 1), dim3(128), 0, stream, W, bias, tune, wtbt);
    hipLaunchKernelGGL(k1_part, dim3(NSLICE, NB), dim3(256), 0, stream, V, gsz, wtbt, part);
    hipLaunchKernelGGL(k2_out, dim3(NB, NH), dim3(128), 0, stream, part, W, bias, out);
}

// Round 20
// 48.495 us; speedup vs baseline: 1.5993x; 1.3357x over previous
//
#include <hip/hip_runtime.h>

#define NB 64
#define NN 4096
#define NC 128
#define NH 4
#define HC (NH * NC)        // 512
#define PSTRIDE (8 + HC)    // 520 floats per partial
#define NSLICE 16           // 16*64 = 1024 blocks
#define TROWS 64            // rows per tile (32 KB); double-buffered = 64 KB LDS
#define LRELU 0.2f

// async global->LDS, 16B per lane per call (no VGPR round-trip)
__device__ __forceinline__ void gload16(const float* g, float* l)
{
    __builtin_amdgcn_global_load_lds(
        (const __attribute__((address_space(1))) void*)g,
        (__attribute__((address_space(3))) void*)l, 16, 0, 0);
}

// ---------------- k0: wt[k][h] = sum_c W[k, h*C+c] * t[h,c];  bt[h] = sum_c bias*t.
__global__ __launch_bounds__(128) void k0_wt(const float* __restrict__ W,
                                             const float* __restrict__ bias,
                                             const float* __restrict__ tune,
                                             float* __restrict__ wtbt)
{
    const int bid = blockIdx.x;
    const int t = threadIdx.x;                       // 0..127
    const float* src = (bid < NC) ? (W + (size_t)bid * HC) : bias;
    float* dst = (bid < NC) ? (wtbt + bid * NH) : (wtbt + NC * NH);
    const float4 a = reinterpret_cast<const float4*>(src)[t];
    const float4 b = reinterpret_cast<const float4*>(tune)[t];
    float p = a.x * b.x + a.y * b.y + a.z * b.z + a.w * b.w;
    #pragma unroll
    for (int off = 16; off; off >>= 1) p += __shfl_xor(p, off, 32);
    if ((t & 31) == 0) dst[t >> 5] = p;              // group t>>5 == head h
}

// ---------------- k1: r15's LDS-staged loop, staging replaced by async DMA
// (global_load_lds, 16B/lane) into a 2x32KB double buffer. Per tile:
// {issue next tile's DMA -> compute current from LDS -> barrier(drains vmcnt)}.
// Zero staging VGPRs; loads get a full compute phase + barrier to land.
__global__ __launch_bounds__(256, 4) void k1_part(const float* __restrict__ V,
                                                  const int* __restrict__ gs,
                                                  const float* __restrict__ wtbt,
                                                  float* __restrict__ part)
{
    __shared__ float smem[2 * TROWS * NC];           // 64 KB; reused for combine
    float (*Sall)[NH][132] = reinterpret_cast<float(*)[NH][132]>(smem); // [8][4][132]
    float* llds = smem + 8 * NH * 132;               // 32 floats

    const int slice = blockIdx.x;
    const int b = blockIdx.y;
    const int tid = threadIdx.x;
    const int hw = tid >> 5;          // half-wave 0..7
    const int lane = tid & 31;
    const int h = lane >> 3;          // head 0..3
    const int j = lane & 7;           // feature-group (features 16j..16j+15)
    const int gsz = gs[b];

    float wtk[16];
    #pragma unroll
    for (int u = 0; u < 16; ++u) wtk[u] = wtbt[(16 * j + u) * NH + h];
    const float bt = wtbt[HC + h];

    const int segB = (gsz + NSLICE - 1) / NSLICE;    // rows per block
    const int myBeg = slice * segB;
    int myEnd = myBeg + segB;
    if (myEnd > gsz) myEnd = gsz;
    const int nrows = (myEnd > myBeg) ? (myEnd - myBeg) : 0;
    const int ntile = (nrows + TROWS - 1) / TROWS;

    float l = 0.f;
    float S[16] = {};

    const size_t gbase = (size_t)b * NN;

    // ---- prologue: DMA tile 0 into buffer 0, wait (barrier drains vmcnt)
    if (ntile > 0) {
        #pragma unroll
        for (int c = 0; c < 8; ++c) {                // 8 x 4KB call sets = 32 KB
            const int idx = c * 256 + tid;           // 16B-chunk index
            const int gr = myBeg + (idx >> 5);
            const int src_row = (gr < myEnd) ? gr : myBeg;
            gload16(V + (gbase + src_row) * NC + (idx & 31) * 4, smem + idx * 4);
        }
    }
    __syncthreads();

    int cur = 0;
    for (int tile = 0; tile < ntile; ++tile) {
        const int tbase = myBeg + tile * TROWS;
        // ---- issue next tile's DMA into the other buffer (flies under compute)
        if (tile + 1 < ntile) {
            float* nb = smem + (cur ^ 1) * (TROWS * NC);
            const int nbase = tbase + TROWS;
            #pragma unroll
            for (int c = 0; c < 8; ++c) {
                const int idx = c * 256 + tid;
                const int gr = nbase + (idx >> 5);
                const int src_row = (gr < myEnd) ? gr : myBeg;
                gload16(V + (gbase + src_row) * NC + (idx & 31) * 4, nb + idx * 4);
            }
        }
        // ---- compute current tile from LDS: half-wave hw owns rows hw*8..hw*8+7
        const float* Vt = smem + cur * (TROWS * NC);
        #pragma unroll 2
        for (int rr = 0; rr < 8; ++rr) {
            const int row = (hw << 3) + rr;
            const bool valid = (tbase + row < myEnd);
            const float4* vr = reinterpret_cast<const float4*>(Vt + row * NC + j * 16);
            const float4 A0 = vr[0];
            const float4 A1 = vr[1];
            const float4 A2 = vr[2];
            const float4 A3 = vr[3];
            float a0 = A0.x * wtk[0]  + A0.y * wtk[1]  + A0.z * wtk[2]  + A0.w * wtk[3];
            float a1 = A1.x * wtk[4]  + A1.y * wtk[5]  + A1.z * wtk[6]  + A1.w * wtk[7];
            float a2 = A2.x * wtk[8]  + A2.y * wtk[9]  + A2.z * wtk[10] + A2.w * wtk[11];
            float a3 = A3.x * wtk[12] + A3.y * wtk[13] + A3.z * wtk[14] + A3.w * wtk[15];
            float lg = (a0 + a1) + (a2 + a3);
            lg += __shfl_xor(lg, 1, 32);
            lg += __shfl_xor(lg, 2, 32);
            lg += __shfl_xor(lg, 4, 32);   // 8-lane head group holds full logit
            float x = lg + bt;
            x = (x >= 0.f) ? x : LRELU * x;           // leaky_relu
            float p = __expf(x);                      // no max subtraction
            p = valid ? p : 0.f;
            l += p;
            S[0]  += p * A0.x;  S[1]  += p * A0.y;  S[2]  += p * A0.z;  S[3]  += p * A0.w;
            S[4]  += p * A1.x;  S[5]  += p * A1.y;  S[6]  += p * A1.z;  S[7]  += p * A1.w;
            S[8]  += p * A2.x;  S[9]  += p * A2.y;  S[10] += p * A2.z;  S[11] += p * A2.w;
            S[12] += p * A3.x;  S[13] += p * A3.y;  S[14] += p * A3.z;  S[15] += p * A3.w;
        }
        __syncthreads();        // drains vmcnt: next tile's DMA durable; buffer safe
        cur ^= 1;
    }

    // ---- block combine across 8 half-waves (smem reused: Sall/llds)
    if (j == 0) llds[hw * NH + h] = l;
    #pragma unroll
    for (int t = 0; t < 4; ++t) {
        float4 s4;
        s4.x = S[4 * t]; s4.y = S[4 * t + 1]; s4.z = S[4 * t + 2]; s4.w = S[4 * t + 3];
        *reinterpret_cast<float4*>(&Sall[hw][h][16 * j + 4 * t]) = s4;
    }
    __syncthreads();
    float* pb = part + (size_t)(b * NSLICE + slice) * PSTRIDE;
    if (tid < 4) {
        float L = 0.f;
        #pragma unroll
        for (int ww = 0; ww < 8; ++ww) L += llds[ww * NH + tid];
        pb[4 + tid] = L;
    }
    #pragma unroll
    for (int r2 = 0; r2 < 2; ++r2) {
        const int e = tid + r2 * 256;
        const int hh = e >> 7, k = e & 127;
        float s = 0.f;
        #pragma unroll
        for (int ww = 0; ww < 8; ++ww) s += Sall[ww][hh][k];
        pb[8 + e] = s;
    }
}

// ---------------- k2: block (b, h): merge NSLICE partials for head h, then
// out[b, h*128+d] = (S[h]/L[h]) . W[:, h*128+d] + bias[h*128+d]
__global__ __launch_bounds__(128) void k2_out(const float* __restrict__ part,
                                              const float* __restrict__ W,
                                              const float* __restrict__ bias,
                                              float* __restrict__ out)
{
    const int b = blockIdx.x;
    const int h = blockIdx.y;
    const int tid = threadIdx.x;     // 0..127
    const float* pb = part + (size_t)b * NSLICE * PSTRIDE;

    __shared__ float Sn[NC];
    __shared__ float sL;
    if (tid == 0) {
        float L = 0.f;
        #pragma unroll
        for (int c = 0; c < NSLICE; ++c) L += pb[(size_t)c * PSTRIDE + 4 + h];
        sL = L;
    }
    __syncthreads();
    {
        float s = 0.f;
        #pragma unroll 4
        for (int c = 0; c < NSLICE; ++c)
            s += pb[(size_t)c * PSTRIDE + 8 + h * NC + tid];
        Sn[tid] = s / sL;
    }
    __syncthreads();
    const int d = h * NC + tid;
    float acc = 0.f;
    #pragma unroll 4
    for (int k = 0; k < NC; ++k) acc += Sn[k] * W[(size_t)k * HC + d];
    out[(size_t)b * HC + d] = acc + bias[d];
}

extern "C" void kernel_launch(void* const* d_in, const int* in_sizes, int n_in,
                              void* d_out, int out_size, void* d_ws, size_t ws_size,
                              hipStream_t stream)
{
    const float* V    = (const float*)d_in[0];
    const int*   gsz  = (const int*)d_in[1];
    const float* W    = (const float*)d_in[2];
    const float* bias = (const float*)d_in[3];
    const float* tune = (const float*)d_in[4];
    float* out  = (float*)d_out;
    float* wtbt = (float*)d_ws;            // 520 floats (516 used)
    float* part = wtbt + PSTRIDE;          // NB*NSLICE*PSTRIDE floats (~2.1 MB)

    hipLaunchKernelGGL(k0_wt, dim3(NC + 1), dim3(128), 0, stream, W, bias, tune, wtbt);
    hipLaunchKernelGGL(k1_part, dim3(NSLICE, NB), dim3(256), 0, stream, V, gsz, wtbt, part);
    hipLaunchKernelGGL(k2_out, dim3(NB, NH), dim3(128), 0, stream, part, W, bias, out);
}